// Round 5
// baseline (479.940 us; speedup 1.0000x reference)
//
#include <hip/hip_runtime.h>

typedef unsigned int u32;
typedef unsigned short u16;
typedef __attribute__((ext_vector_type(8))) short short8;
typedef __attribute__((ext_vector_type(4))) float f4;

#define MFMA(a, b, c) __builtin_amdgcn_mfma_f32_16x16x32_bf16((a), (b), (c), 0, 0, 0)
#define LL 384
#define NPAIR 147456

// ---- helpers ----
__device__ __forceinline__ u16 f2bf(float f) {
    u32 u = __float_as_uint(f);
    u = (u + 0x7fffu + ((u >> 16) & 1u)) >> 16;
    return (u16)u;
}
// RNE pack of two f32 -> bf16x2 in pure C (compiler-generated VALU: hazards
// with downstream MFMA are compiler-managed; inline-asm cvt_pk feeding MFMA
// directly produced NaN in R4 — suspected missed VALU->MFMA wait states).
__device__ __forceinline__ u32 pack2(float a, float b) {
    u32 ua = __float_as_uint(a); ua = (ua + 0x7fffu + ((ua >> 16) & 1u)) >> 16;
    u32 ub = __float_as_uint(b); ub = (ub + 0x7fffu + ((ub >> 16) & 1u)) >> 16;
    return ua | (ub << 16);
}
__device__ __forceinline__ short8 ld8(const u16* p) { return *reinterpret_cast<const short8*>(p); }
__device__ __forceinline__ short8 to8(u32 a, u32 b, u32 c, u32 d) {
    union { u32 u[4]; short8 s; } x; x.u[0] = a; x.u[1] = b; x.u[2] = c; x.u[3] = d; return x.s;
}
// build bf16x8 A-fragment from two float4 (8 consecutive f32)
__device__ __forceinline__ short8 frag8(float4 c0, float4 c1) {
    return to8(pack2(c0.x, c0.y), pack2(c0.z, c0.w), pack2(c1.x, c1.y), pack2(c1.z, c1.w));
}

// 16-lane sum on the VALU pipe (DPP): quad_perm xor1/xor2 + row_ror:4/8.
template <int CTRL>
__device__ __forceinline__ float dpp_add(float v) {
    int t = __builtin_amdgcn_update_dpp(0, __float_as_int(v), CTRL, 0xf, 0xf, true);
    return v + __int_as_float(t);
}
__device__ __forceinline__ float red16(float v) {
    v = dpp_add<0xB1>(v);    // quad_perm [1,0,3,2]  (xor 1)
    v = dpp_add<0x4E>(v);    // quad_perm [2,3,0,1]  (xor 2)
    v = dpp_add<0x124>(v);   // row_ror:4
    v = dpp_add<0x128>(v);   // row_ror:8
    return v;
}

// XOR swizzle for the o-exchange tile (128B rows): conflict-free column reads.
__device__ __forceinline__ int swz128(int row, int bcol) {
    return row * 128 + (bcol ^ ((row & 7) << 4));
}

// ---- workspace layout ----
// u16 region: [0,8192) WqSW  [8192,12288) WkSW  [12288,16384) WvSW  [16384,24576) WoSW
// float region (float idx): [12288..] GQ BQ GK BK GV BV (64 each), bo at 12672 (128)
// swizzle: sw[(k>>3)*N*8 + n*8 + (k&7)] = W'[k][n]

__global__ void prep_w(const float* __restrict__ Wq, const float* __restrict__ Wk,
                       const float* __restrict__ Wv, const float* __restrict__ Wo,
                       const float* __restrict__ zg, const float* __restrict__ tg,
                       float* __restrict__ ws) {
    int idx = blockIdx.x * blockDim.x + threadIdx.x;
    u16* wsu = (u16*)ws;
    if (idx < 8192) {               // WqSW, N=64, K=128, fold zg
        int kb = idx >> 9, rem = idx & 511, n = rem >> 3, j = rem & 7, k = kb * 8 + j;
        wsu[idx] = f2bf(Wq[k * 64 + n] * zg[k]);
    } else if (idx < 12288) {       // WkSW, N=64, K=64, fold tg
        int e = idx - 8192;
        int kb = e >> 9, rem = e & 511, n = rem >> 3, j = rem & 7, k = kb * 8 + j;
        wsu[idx] = f2bf(Wk[k * 64 + n] * tg[k]);
    } else if (idx < 16384) {       // WvSW
        int e = idx - 12288;
        int kb = e >> 9, rem = e & 511, n = rem >> 3, j = rem & 7, k = kb * 8 + j;
        wsu[idx] = f2bf(Wv[k * 64 + n] * tg[k]);
    } else if (idx < 24576) {       // WoSW, N=128, K=64, no fold
        int e = idx - 16384;
        int kb = e >> 10, rem = e & 1023, n = rem >> 3, j = rem & 7, k = kb * 8 + j;
        wsu[idx] = f2bf(Wo[k * 128 + n]);
    }
}

__global__ void prep_aux(const float* __restrict__ Wq, const float* __restrict__ Wk,
                         const float* __restrict__ Wv, const float* __restrict__ zg,
                         const float* __restrict__ zb, const float* __restrict__ tg,
                         const float* __restrict__ tb, const float* __restrict__ bo,
                         float* __restrict__ ws) {
    int idx = blockIdx.x * blockDim.x + threadIdx.x;
    if (idx < 384) {
        int g = idx >> 6, hc = idx & 63;
        float acc = 0.f;
        if (g == 0)      { for (int d = 0; d < 128; ++d) acc += zg[d] * Wq[d*64+hc]; ws[12288+hc] = acc; }
        else if (g == 1) { for (int d = 0; d < 128; ++d) acc += zb[d] * Wq[d*64+hc]; ws[12352+hc] = acc; }
        else if (g == 2) { for (int d = 0; d < 64;  ++d) acc += tg[d] * Wk[d*64+hc]; ws[12416+hc] = acc; }
        else if (g == 3) { for (int d = 0; d < 64;  ++d) acc += tb[d] * Wk[d*64+hc]; ws[12480+hc] = acc; }
        else if (g == 4) { for (int d = 0; d < 64;  ++d) acc += tg[d] * Wv[d*64+hc]; ws[12544+hc] = acc; }
        else             { for (int d = 0; d < 64;  ++d) acc += tb[d] * Wv[d*64+hc]; ws[12608+hc] = acc; }
    } else if (idx < 512) {
        ws[12672 + idx - 384] = bo[idx - 384];
    }
}

// block = 256 threads (4 waves), M = 32 pairs/block, grid = 4608
// Fragment-direct: A-operands loaded straight from global f32 (L2-hot tile)
// in MFMA fragment order, converted with compiler-generated RNE bit-packs.
// LN stats from the same registers via shfl_xor(16/32) reduce. NO staging
// LDS, ONE barrier (o-exchange) -> waves run desynchronized chains.
__global__ __launch_bounds__(256, 4) void tpa_main(
    const float* __restrict__ tmpl,   // [4][147456][64]
    const float* __restrict__ z,      // [147456][128]
    const float* __restrict__ mask,   // [4][384]
    const float* __restrict__ ws,
    float* __restrict__ out)          // [147456][128]
{
    __shared__ __align__(16) u16 sO[32 * 64];   // o-exchange tile, swizzled 128B rows

    const int tid = threadIdx.x;
    const int p0 = blockIdx.x * 32;
    const u16* wsu = (const u16*)ws;
    const float* wsf = ws;
    char* sOb = (char*)sO;

    // wave partition: rt = row-tile (16 rows), nh = n-half (2 head-tiles)
    const int wave = tid >> 6, lane = tid & 63, g = lane >> 4, l15 = lane & 15;
    const int rt = wave & 1, nh = wave >> 1;
    const int rowA = rt * 16 + l15;        // A-row this lane feeds
    const int gp = p0 + rowA;              // global pair index of that row
    const int col0 = (2 * nh) * 16 + l15, col1 = (2 * nh + 1) * 16 + l15;
    int rowC[4];
    #pragma unroll
    for (int r = 0; r < 4; ++r) rowC[r] = rt * 16 + g * 4 + r;

    // aux scalars (3KB ws region, L1-hot)
    float GK0 = wsf[12416 + col0], GK1 = wsf[12416 + col1];
    float BK0 = wsf[12480 + col0], BK1 = wsf[12480 + col1];

    // ================= phase Q: q GEMM direct from z =================
    // lane(g,l15) loads z[gp][ks*32+g*8 .. +8]  (32B coalesced)
    f4 aq0 = {0.f,0.f,0.f,0.f}, aq1 = {0.f,0.f,0.f,0.f};
    float s = 0.f, ss = 0.f;
    {
        const float4* zp = (const float4*)(z + (size_t)gp * 128);
        #pragma unroll
        for (int ks = 0; ks < 4; ++ks) {
            float4 c0 = zp[ks * 8 + g * 2], c1 = zp[ks * 8 + g * 2 + 1];
            s  += c0.x+c0.y+c0.z+c0.w + c1.x+c1.y+c1.z+c1.w;
            ss += c0.x*c0.x+c0.y*c0.y+c0.z*c0.z+c0.w*c0.w
                + c1.x*c1.x+c1.y*c1.y+c1.z*c1.z+c1.w*c1.w;
            short8 A = frag8(c0, c1);
            const u16* wb = wsu + (ks * 4 + g) * 512;
            aq0 = MFMA(A, ld8(wb + col0 * 8), aq0);
            aq1 = MFMA(A, ld8(wb + col1 * 8), aq1);
        }
    }
    // row stats: reduce over the 4 g-copies of each row (lanes ±16, ±32)
    s += __shfl_xor(s, 16); ss += __shfl_xor(ss, 16);
    s += __shfl_xor(s, 32); ss += __shfl_xor(ss, 32);
    float qv[2][4];
    {
        float zmu = s * (1.f / 128.f);
        float zvar = fmaf(-zmu, zmu, ss * (1.f / 128.f));
        float zr = rsqrtf(zvar + 1e-5f), zrm = zr * zmu;
        float GQ0 = wsf[12288 + col0], GQ1 = wsf[12288 + col1];
        float BQ0 = wsf[12352 + col0], BQ1 = wsf[12352 + col1];
        #pragma unroll
        for (int r = 0; r < 4; ++r) {
            int src = g * 4 + r;                    // lane holding row rowC[r]'s stat
            float zrS = __shfl(zr, src), zmS = __shfl(zrm, src);
            qv[0][r] = 0.25f * fmaf(zrS, aq0[r], fmaf(-zmS, GQ0, BQ0));
            qv[1][r] = 0.25f * fmaf(zrS, aq1[r], fmaf(-zmS, GQ1, BQ1));
        }
    }

    // ================= phase K: k GEMMs + logits, direct from t =================
    // logit = qv·(tr*k - tm*GK + BK); tr,tm per t-row via shfl broadcast.
    float lg[4][2][4];      // logits; reused as attention weights after softmax
    float trS[4][4], tmS[4][4];
    const u16* wk = wsu + 8192;
    {
        short8 Bk00 = ld8(wk + g * 512 + col0 * 8);
        short8 Bk01 = ld8(wk + g * 512 + col1 * 8);
        short8 Bk10 = ld8(wk + (4 + g) * 512 + col0 * 8);
        short8 Bk11 = ld8(wk + (4 + g) * 512 + col1 * 8);
        #pragma unroll
        for (int tt = 0; tt < 4; ++tt) {
            const float4* tp = (const float4*)(tmpl + ((size_t)tt * NPAIR + gp) * 64);
            float4 c0 = tp[g * 2], c1 = tp[g * 2 + 1];         // ks=0: elems g*8..+8
            float4 c2 = tp[8 + g * 2], c3 = tp[8 + g * 2 + 1]; // ks=1: elems 32+g*8..+8
            float s2  = c0.x+c0.y+c0.z+c0.w + c1.x+c1.y+c1.z+c1.w
                      + c2.x+c2.y+c2.z+c2.w + c3.x+c3.y+c3.z+c3.w;
            float ss2 = c0.x*c0.x+c0.y*c0.y+c0.z*c0.z+c0.w*c0.w
                      + c1.x*c1.x+c1.y*c1.y+c1.z*c1.z+c1.w*c1.w
                      + c2.x*c2.x+c2.y*c2.y+c2.z*c2.z+c2.w*c2.w
                      + c3.x*c3.x+c3.y*c3.y+c3.z*c3.z+c3.w*c3.w;
            s2 += __shfl_xor(s2, 16); ss2 += __shfl_xor(ss2, 16);
            s2 += __shfl_xor(s2, 32); ss2 += __shfl_xor(ss2, 32);
            float mu = s2 * (1.f / 64.f);
            float var = fmaf(-mu, mu, ss2 * (1.f / 64.f));
            float rr = rsqrtf(var + 1e-5f), rm = rr * mu;
            short8 A0 = frag8(c0, c1), A1 = frag8(c2, c3);
            f4 k0 = {0.f,0.f,0.f,0.f}, k1 = {0.f,0.f,0.f,0.f};
            k0 = MFMA(A0, Bk00, k0); k1 = MFMA(A0, Bk01, k1);
            k0 = MFMA(A1, Bk10, k0); k1 = MFMA(A1, Bk11, k1);
            #pragma unroll
            for (int r = 0; r < 4; ++r) {
                int src = g * 4 + r;
                float tr = __shfl(rr, src), tm = __shfl(rm, src);
                trS[tt][r] = tr; tmS[tt][r] = tm;
                float kc0 = fmaf(tr, k0[r], fmaf(-tm, GK0, BK0));
                float kc1 = fmaf(tr, k1[r], fmaf(-tm, GK1, BK1));
                lg[tt][0][r] = red16(qv[0][r] * kc0);
                lg[tt][1][r] = red16(qv[1][r] * kc1);
            }
        }
    }

    // ================= softmax over T (in-lane, no max-shift) =================
    // logits O(0.3) -> exp safe; exp->mask->renorm is shift-invariant.
    // lg is overwritten in place with ap = a * tr (v-row LN scale folded in).
    float cb[2][4], cg[2][4];
    #pragma unroll
    for (int r = 0; r < 4; ++r) {
        int p = p0 + rowC[r], i = p / LL, j = p - i * LL;
        float pmA[4];
        #pragma unroll
        for (int tt = 0; tt < 4; ++tt) pmA[tt] = mask[tt * LL + i] * mask[tt * LL + j];
        #pragma unroll
        for (int nn = 0; nn < 2; ++nn) {
            float e0 = __expf(lg[0][nn][r]) * pmA[0];
            float e1 = __expf(lg[1][nn][r]) * pmA[1];
            float e2 = __expf(lg[2][nn][r]) * pmA[2];
            float e3 = __expf(lg[3][nn][r]) * pmA[3];
            float sm = (e0 + e1) + (e2 + e3);
            float rr2 = __builtin_amdgcn_rcpf(fmaxf(sm, 1e-20f));
            float a0 = e0 * rr2, a1 = e1 * rr2, a2 = e2 * rr2, a3 = e3 * rr2;
            cb[nn][r] = sm * rr2;   // 1 if any unmasked, else 0
            cg[nn][r] = a0 * tmS[0][r] + a1 * tmS[1][r] + a2 * tmS[2][r] + a3 * tmS[3][r];
            lg[0][nn][r] = a0 * trS[0][r];
            lg[1][nn][r] = a1 * trS[1][r];
            lg[2][nn][r] = a2 * trS[2][r];
            lg[3][nn][r] = a3 * trS[3][r];
        }
    }

    // ================= phase V: v GEMMs direct from t + weighted accumulate ====
    float o0[4] = {0.f,0.f,0.f,0.f}, o1[4] = {0.f,0.f,0.f,0.f};
    {
        const u16* wv = wsu + 12288;
        short8 Bv00 = ld8(wv + g * 512 + col0 * 8);
        short8 Bv01 = ld8(wv + g * 512 + col1 * 8);
        short8 Bv10 = ld8(wv + (4 + g) * 512 + col0 * 8);
        short8 Bv11 = ld8(wv + (4 + g) * 512 + col1 * 8);
        #pragma unroll
        for (int tt = 0; tt < 4; ++tt) {
            const float4* tp = (const float4*)(tmpl + ((size_t)tt * NPAIR + gp) * 64);
            short8 A0 = frag8(tp[g * 2], tp[g * 2 + 1]);          // L1/L2-hot reload
            short8 A1 = frag8(tp[8 + g * 2], tp[8 + g * 2 + 1]);
            f4 v0 = {0.f,0.f,0.f,0.f}, v1 = {0.f,0.f,0.f,0.f};
            v0 = MFMA(A0, Bv00, v0); v1 = MFMA(A0, Bv01, v1);
            v0 = MFMA(A1, Bv10, v0); v1 = MFMA(A1, Bv11, v1);
            #pragma unroll
            for (int r = 0; r < 4; ++r) {
                o0[r] = fmaf(lg[tt][0][r], v0[r], o0[r]);
                o1[r] = fmaf(lg[tt][1][r], v1[r], o1[r]);
            }
        }
        float GV0 = wsf[12544 + col0], GV1 = wsf[12544 + col1];
        float BV0 = wsf[12608 + col0], BV1 = wsf[12608 + col1];
        #pragma unroll
        for (int r = 0; r < 4; ++r) {   // LN affine correction for v
            o0[r] = fmaf(cb[0][r], BV0, fmaf(-cg[0][r], GV0, o0[r]));
            o1[r] = fmaf(cb[1][r], BV1, fmaf(-cg[1][r], GV1, o1[r]));
        }
    }

    // ================= o-exchange (the only barrier) =================
    #pragma unroll
    for (int r = 0; r < 4; ++r) {
        u32 p = pack2(o0[r], o1[r]);
        *(u16*)(sOb + swz128(rowC[r], col0 * 2)) = (u16)p;
        *(u16*)(sOb + swz128(rowC[r], col1 * 2)) = (u16)(p >> 16);
    }
    __syncthreads();

    // ================= phase O: out GEMM [32x64]@[64x128] =================
    {
        const u16* wo = wsu + 16384;
        const int nb = nh * 4;               // 4 n-tiles per wave
        f4 c0 = {0.f,0.f,0.f,0.f}, c1 = {0.f,0.f,0.f,0.f};
        f4 c2 = {0.f,0.f,0.f,0.f}, c3 = {0.f,0.f,0.f,0.f};
        #pragma unroll
        for (int ks = 0; ks < 2; ++ks) {
            short8 A = ld8((const u16*)(sOb + swz128(rowA, (ks * 4 + g) * 16)));
            const u16* wb = wo + (ks * 4 + g) * 1024;
            c0 = MFMA(A, ld8(wb + ((nb + 0) * 16 + l15) * 8), c0);
            c1 = MFMA(A, ld8(wb + ((nb + 1) * 16 + l15) * 8), c1);
            c2 = MFMA(A, ld8(wb + ((nb + 2) * 16 + l15) * 8), c2);
            c3 = MFMA(A, ld8(wb + ((nb + 3) * 16 + l15) * 8), c3);
        }
        #pragma unroll
        for (int r = 0; r < 4; ++r) {
            int row = p0 + rowC[r];
            float* op = out + (size_t)row * 128;
            op[(nb + 0) * 16 + l15] = c0[r] + wsf[12672 + (nb + 0) * 16 + l15];
            op[(nb + 1) * 16 + l15] = c1[r] + wsf[12672 + (nb + 1) * 16 + l15];
            op[(nb + 2) * 16 + l15] = c2[r] + wsf[12672 + (nb + 2) * 16 + l15];
            op[(nb + 3) * 16 + l15] = c3[r] + wsf[12672 + (nb + 3) * 16 + l15];
        }
    }
}

extern "C" void kernel_launch(void* const* d_in, const int* in_sizes, int n_in,
                              void* d_out, int out_size, void* d_ws, size_t ws_size,
                              hipStream_t stream) {
    const float* t   = (const float*)d_in[0];
    const float* z   = (const float*)d_in[1];
    const float* msk = (const float*)d_in[2];
    const float* zg  = (const float*)d_in[3];
    const float* zb  = (const float*)d_in[4];
    const float* tg  = (const float*)d_in[5];
    const float* tb  = (const float*)d_in[6];
    const float* Wq  = (const float*)d_in[7];
    const float* Wk  = (const float*)d_in[8];
    const float* Wv  = (const float*)d_in[9];
    const float* Wo  = (const float*)d_in[10];
    const float* bo  = (const float*)d_in[11];
    float* ws = (float*)d_ws;

    prep_w<<<96, 256, 0, stream>>>(Wq, Wk, Wv, Wo, zg, tg, ws);
    prep_aux<<<2, 256, 0, stream>>>(Wq, Wk, Wv, zg, zb, tg, tb, bo, ws);
    tpa_main<<<4608, 256, 0, stream>>>(t, z, msk, ws, (float*)d_out);
}